// Round 1
// baseline (398.203 us; speedup 1.0000x reference)
//
#include <hip/hip_runtime.h>
#include <math.h>

#define NN 20000
#define EE 100000
#define CC 256
#define EDM 16
#define RC 4
#define MTOT (RC * NN)   // 80000

typedef __attribute__((ext_vector_type(8))) short short8;
typedef __attribute__((ext_vector_type(4))) float floatx4;

#define LDK 72   // LDS k-stride in bf16 (64 + 8 pad) -> 36 dwords, conflict-free b128

__device__ __forceinline__ unsigned short f2bf(float f) {
    union { float f; unsigned u; } v; v.f = f;
    unsigned r = v.u + 0x7FFF + ((v.u >> 16) & 1);   // RNE
    return (unsigned short)(r >> 16);
}
__device__ __forceinline__ float bf2f(unsigned short h) {
    union { unsigned u; float f; } v; v.u = ((unsigned)h) << 16;
    return v.f;
}

// GELU(exact-erf) via Abramowitz-Stegun 7.1.26 (|erf err| < 1.5e-7).
__device__ __forceinline__ float gelu_fast(float v) {
    const float ax = fabsf(v) * 0.70710678118654752f;
    const float t  = __builtin_amdgcn_rcpf(fmaf(0.3275911f, ax, 1.0f));
    const float p  = t * fmaf(t, fmaf(t, fmaf(t, fmaf(t, 1.061405429f,
                                -1.453152027f), 1.421413741f), -0.284496736f),
                              0.254829592f);
    const float e  = __builtin_amdgcn_exp2f(ax * ax * -1.4426950408889634f);
    const float erf_ax = fmaf(-p, e, 1.0f);
    return fmaf(0.5f * fabsf(v), erf_ax, 0.5f * v);
}

// ---------------------------------------------------------------------------
// fused prep (weight transpose+bf16) + per-dst edge count
// ---------------------------------------------------------------------------
__global__ void k_prep_count(const float* __restrict__ lin_W,
                             const float* __restrict__ linl_W,
                             const float* __restrict__ linr_W,
                             unsigned short* __restrict__ linWT,
                             unsigned short* __restrict__ WbT,
                             const int* __restrict__ eidx,
                             int* __restrict__ cnt) {
    const int b = blockIdx.x;
    const int t = threadIdx.x;
    if (b < CC) {
        linWT[b * CC + t]      = f2bf(lin_W[t * CC + b]);
        WbT[b * 512 + t]       = f2bf(linl_W[t * CC + b]);
        WbT[b * 512 + 256 + t] = f2bf(linr_W[t * CC + b]);
    } else {
        int e = (b - CC) * 256 + t;
        if (e < EE) atomicAdd(cnt + eidx[EE + e], 1);
    }
}

// ---------------------------------------------------------------------------
// MFMA GEMM: C[M x 256] = concat_k(A1, A2)[M x KTOT] @ B[KTOT x 256] + bias
// A1 can be fp32 (A1BF16=0) or bf16 (A1BF16=1). A2 always fp32.
// ---------------------------------------------------------------------------
template <int KTOT, int OUTBF16, int A1BF16>
__global__ __launch_bounds__(256) void k_mm(const float* __restrict__ A1f,
                                            const unsigned short* __restrict__ A1b,
                                            const float* __restrict__ A2,
                                            const unsigned short* __restrict__ BT,
                                            const float* __restrict__ bias,
                                            float* __restrict__ Cf,
                                            unsigned short* __restrict__ Cb) {
    __shared__ unsigned short As[64 * LDK];
    __shared__ unsigned short Bs[256 * LDK];
    const int tid  = threadIdx.x;
    const int lane = tid & 63;
    const int wave = tid >> 6;
    const int i0   = blockIdx.x * 64;
    const int l15  = lane & 15;
    const int q4   = lane >> 4;   // 0..3

    floatx4 acc[4][4];
#pragma unroll
    for (int mt = 0; mt < 4; mt++)
#pragma unroll
        for (int nt = 0; nt < 4; nt++) acc[mt][nt] = (floatx4)0.0f;

    for (int kc = 0; kc < KTOT; kc += 64) {
        __syncthreads();
        const int first = (kc < 256);
        const int kco   = first ? kc : kc - 256;
#pragma unroll
        for (int it = 0; it < 2; it++) {
            int q = tid + it * 256;
            int r = q >> 3;
            int c = q & 7;
            if (A1BF16 && first) {
                *(uint4*)(As + r * LDK + c * 8) =
                    *(const uint4*)(A1b + (size_t)(i0 + r) * CC + kco + c * 8);
            } else {
                const float* src = (first ? A1f : A2) + (size_t)(i0 + r) * CC + kco + c * 8;
                float4 v0 = *(const float4*)(src);
                float4 v1 = *(const float4*)(src + 4);
                uint4 p;
                p.x = (unsigned)f2bf(v0.x) | ((unsigned)f2bf(v0.y) << 16);
                p.y = (unsigned)f2bf(v0.z) | ((unsigned)f2bf(v0.w) << 16);
                p.z = (unsigned)f2bf(v1.x) | ((unsigned)f2bf(v1.y) << 16);
                p.w = (unsigned)f2bf(v1.z) | ((unsigned)f2bf(v1.w) << 16);
                *(uint4*)(As + r * LDK + c * 8) = p;
            }
        }
#pragma unroll
        for (int it = 0; it < 8; it++) {
            int q = tid + it * 256;
            int n = q >> 3;
            int c = q & 7;
            *(uint4*)(Bs + n * LDK + c * 8) =
                *(const uint4*)(BT + (size_t)n * KTOT + kc + c * 8);
        }
        __syncthreads();
#pragma unroll
        for (int kk = 0; kk < 64; kk += 32) {
            short8 a[4], b[4];
#pragma unroll
            for (int mt = 0; mt < 4; mt++)
                a[mt] = *(const short8*)(As + (mt * 16 + l15) * LDK + kk + q4 * 8);
#pragma unroll
            for (int nt = 0; nt < 4; nt++)
                b[nt] = *(const short8*)(Bs + (wave * 64 + nt * 16 + l15) * LDK + kk + q4 * 8);
#pragma unroll
            for (int mt = 0; mt < 4; mt++)
#pragma unroll
                for (int nt = 0; nt < 4; nt++)
                    acc[mt][nt] = __builtin_amdgcn_mfma_f32_16x16x32_bf16(
                        a[mt], b[nt], acc[mt][nt], 0, 0, 0);
        }
    }
    // C/D layout: col=lane&15, row=(lane>>4)*4+reg  [verified m89/m91]
#pragma unroll
    for (int nt = 0; nt < 4; nt++) {
        const int col = wave * 64 + nt * 16 + l15;
        const float bz = bias[col];
#pragma unroll
        for (int mt = 0; mt < 4; mt++) {
#pragma unroll
            for (int r = 0; r < 4; r++) {
                const int row = i0 + mt * 16 + q4 * 4 + r;
                const float v = acc[mt][nt][r] + bz;
                if (OUTBF16) Cb[(size_t)row * CC + col] = f2bf(v);
                else         Cf[(size_t)row * CC + col] = v;
            }
        }
    }
}

// ---------------------------------------------------------------------------
// CSR scan + scatter
// ---------------------------------------------------------------------------
#define SCAN_T 1024
#define SCHUNK 20
__global__ __launch_bounds__(1024) void k_scan(const int* __restrict__ cnt,
                                               int* __restrict__ offs,
                                               int* __restrict__ cursor) {
    __shared__ int ps[SCAN_T];
    const int t = threadIdx.x;
    const int base = t * SCHUNK;
    int s = 0;
#pragma unroll
    for (int i = 0; i < SCHUNK; i++) {
        int idx = base + i;
        if (idx < NN) s += cnt[idx];
    }
    ps[t] = s;
    __syncthreads();
    for (int off = 1; off < SCAN_T; off <<= 1) {
        int v = (t >= off) ? ps[t - off] : 0;
        __syncthreads();
        ps[t] += v;
        __syncthreads();
    }
    int excl = (t == 0) ? 0 : ps[t - 1];
#pragma unroll
    for (int i = 0; i < SCHUNK; i++) {
        int idx = base + i;
        if (idx < NN) {
            offs[idx]   = excl;
            cursor[idx] = excl;
            excl += cnt[idx];
        }
    }
    if (t == SCAN_T - 1) offs[NN] = ps[SCAN_T - 1];
}

__global__ void k_scatter(const int* __restrict__ eidx, int* __restrict__ cursor,
                          int* __restrict__ bucket) {
    int e = blockIdx.x * 256 + threadIdx.x;
    if (e < EE) {
        int d = eidx[EE + e];
        int p = atomicAdd(cursor + d, 1);
        bucket[p] = e;
    }
}

// ---------------------------------------------------------------------------
// gather-mean: block = node, thread = channel, 4 rc accumulators per lane.
// Scalarized: bond_W hoisted to 16 regs; e/src via readfirstlane so ea/ew
// loads go down the SMEM (K$) path instead of the TA/vmem pipe.
// ---------------------------------------------------------------------------
template <int MEANBF16>
__global__ __launch_bounds__(256) void k_agg(const unsigned short* __restrict__ xlb,
                                             const float* __restrict__ edge_attr,
                                             const float* __restrict__ ew,
                                             const float* __restrict__ bond_W,
                                             const float* __restrict__ bond_b,
                                             const int* __restrict__ eidx,
                                             const int* __restrict__ offs,
                                             const int* __restrict__ bucket,
                                             float* __restrict__ mean_f,
                                             unsigned short* __restrict__ mean_b) {
    const int n = blockIdx.x;
    const int c = threadIdx.x;
    const int beg = offs[n], end = offs[n + 1];
    const float bb = bond_b[c];
    float bw[EDM];
#pragma unroll
    for (int k = 0; k < EDM; k++) bw[k] = bond_W[k * CC + c];   // loop-invariant

    float a0 = 0.f, a1 = 0.f, a2 = 0.f, a3 = 0.f;

#pragma unroll 2
    for (int j = beg; j < end; j++) {
        const int e   = __builtin_amdgcn_readfirstlane(bucket[j]);
        const int src = __builtin_amdgcn_readfirstlane(eidx[e]);
        const float w0 = ew[e];             // uniform addr -> s_load
        const float w1 = ew[EE + e];
        const float w2 = ew[2 * EE + e];
        const float w3 = ew[3 * EE + e];
        const float* ea = edge_attr + (size_t)e * EDM;
        float emb = bb;
#pragma unroll
        for (int k = 0; k < EDM; k++)
            emb = fmaf(ea[k], bw[k], emb);  // ea scalar, bw/emb VGPR: 1 SGPR/VALU ok
        const size_t sb = (size_t)src * CC + c;
        float v0 = bf2f(xlb[sb])                       + emb;
        float v1 = bf2f(xlb[sb + (size_t)NN * CC])     + emb;
        float v2 = bf2f(xlb[sb + (size_t)2 * NN * CC]) + emb;
        float v3 = bf2f(xlb[sb + (size_t)3 * NN * CC]) + emb;
        a0 += gelu_fast(v0) * w0;
        a1 += gelu_fast(v1) * w1;
        a2 += gelu_fast(v2) * w2;
        a3 += gelu_fast(v3) * w3;
    }
    const float inv = 1.0f / fmaxf((float)(end - beg), 1.0f);
    const size_t ob = (size_t)n * CC + c;
    if (MEANBF16) {
        mean_b[ob]                       = f2bf(a0 * inv);
        mean_b[ob + (size_t)NN * CC]     = f2bf(a1 * inv);
        mean_b[ob + (size_t)2 * NN * CC] = f2bf(a2 * inv);
        mean_b[ob + (size_t)3 * NN * CC] = f2bf(a3 * inv);
    } else {
        mean_f[ob]                       = a0 * inv;
        mean_f[ob + (size_t)NN * CC]     = a1 * inv;
        mean_f[ob + (size_t)2 * NN * CC] = a2 * inv;
        mean_f[ob + (size_t)3 * NN * CC] = a3 * inv;
    }
}

extern "C" void kernel_launch(void* const* d_in, const int* in_sizes, int n_in,
                              void* d_out, int out_size, void* d_ws, size_t ws_size,
                              hipStream_t stream) {
    (void)in_sizes; (void)n_in; (void)out_size;
    const float* x           = (const float*)d_in[0];
    const float* edge_attr   = (const float*)d_in[1];
    const float* edge_weight = (const float*)d_in[2];
    const float* lin_W       = (const float*)d_in[3];
    const float* lin_b       = (const float*)d_in[4];
    const float* linl_W      = (const float*)d_in[5];
    const float* linl_b      = (const float*)d_in[6];
    const float* linr_W      = (const float*)d_in[7];
    const float* bond_W      = (const float*)d_in[8];
    const float* bond_b      = (const float*)d_in[9];
    const int*   edge_index  = (const int*)d_in[10];

    unsigned short* xlb   = (unsigned short*)d_ws;          // 80000*256 bf16
    unsigned short* linWT = xlb + (size_t)MTOT * CC;        // 256*256 bf16
    unsigned short* WbT   = linWT + CC * CC;                // 256*512 bf16
    int* cnt    = (int*)(WbT + CC * 512);                   // N
    int* offs   = cnt + NN;                                 // N+1
    int* cursor = offs + NN + 1;                            // N
    int* bucket = cursor + NN;                              // E
    // bf16 mean buffer, 256B-aligned for uint4 staging loads in k_mm
    uintptr_t mb_addr = (((uintptr_t)(bucket + EE)) + 255) & ~(uintptr_t)255;
    unsigned short* mean_b = (unsigned short*)mb_addr;
    const size_t need = (mb_addr - (uintptr_t)d_ws) + (size_t)MTOT * CC * 2;
    const int use_bf16 = (ws_size >= need);

    hipMemsetAsync(cnt, 0, NN * sizeof(int), stream);

    k_prep_count<<<CC + (EE + 255) / 256, 256, 0, stream>>>(
        lin_W, linl_W, linr_W, linWT, WbT, edge_index, cnt);
    // x_l(bf16) = x @ lin_W + lin_b
    k_mm<256, 1, 0><<<MTOT / 64, 256, 0, stream>>>(x, nullptr, x, linWT, lin_b,
                                                   nullptr, xlb);
    k_scan<<<1, SCAN_T, 0, stream>>>(cnt, offs, cursor);
    k_scatter<<<(EE + 255) / 256, 256, 0, stream>>>(edge_index, cursor, bucket);

    if (use_bf16) {
        // mean stored bf16 (identical RNE rounding to what k_mm staging did)
        k_agg<1><<<NN, 256, 0, stream>>>(xlb, edge_attr, edge_weight, bond_W, bond_b,
                                         edge_index, offs, bucket, nullptr, mean_b);
        // out = mean @ linl_W + linl_b + x @ linr_W   (A1 read as bf16)
        k_mm<512, 0, 1><<<MTOT / 64, 256, 0, stream>>>(nullptr, mean_b, x, WbT, linl_b,
                                                       (float*)d_out, nullptr);
    } else {
        // fallback: fp32 mean in d_out, fused GEMM in-place (row-exact aliasing)
        float* mean = (float*)d_out;
        k_agg<0><<<NN, 256, 0, stream>>>(xlb, edge_attr, edge_weight, bond_W, bond_b,
                                         edge_index, offs, bucket, mean, nullptr);
        k_mm<512, 0, 0><<<MTOT / 64, 256, 0, stream>>>(mean, nullptr, x, WbT, linl_b,
                                                       (float*)d_out, nullptr);
    }
}

// Round 2
// 372.484 us; speedup vs baseline: 1.0690x; 1.0690x over previous
//
#include <hip/hip_runtime.h>
#include <math.h>

#define NN 20000
#define EE 100000
#define CC 256
#define EDM 16
#define RC 4
#define MTOT (RC * NN)   // 80000

typedef __attribute__((ext_vector_type(8))) short short8;
typedef __attribute__((ext_vector_type(4))) float floatx4;

__device__ __forceinline__ unsigned short f2bf(float f) {
    union { float f; unsigned u; } v; v.f = f;
    unsigned r = v.u + 0x7FFF + ((v.u >> 16) & 1);   // RNE
    return (unsigned short)(r >> 16);
}
__device__ __forceinline__ float bf2f(unsigned short h) {
    union { unsigned u; float f; } v; v.u = ((unsigned)h) << 16;
    return v.f;
}

// GELU(exact-erf) via Abramowitz-Stegun 7.1.26 (|erf err| < 1.5e-7).
__device__ __forceinline__ float gelu_fast(float v) {
    const float ax = fabsf(v) * 0.70710678118654752f;
    const float t  = __builtin_amdgcn_rcpf(fmaf(0.3275911f, ax, 1.0f));
    const float p  = t * fmaf(t, fmaf(t, fmaf(t, fmaf(t, 1.061405429f,
                                -1.453152027f), 1.421413741f), -0.284496736f),
                              0.254829592f);
    const float e  = __builtin_amdgcn_exp2f(ax * ax * -1.4426950408889634f);
    const float erf_ax = fmaf(-p, e, 1.0f);
    return fmaf(0.5f * fabsf(v), erf_ax, 0.5f * v);
}

// async global->LDS, 16B per lane; LDS dest is wave-uniform base + lane*16
#define GLDS16(gp, lp)                                                        \
    __builtin_amdgcn_global_load_lds(                                         \
        (const __attribute__((address_space(1))) unsigned int*)(gp),          \
        (__attribute__((address_space(3))) unsigned int*)(lp), 16, 0, 0)

// ---------------------------------------------------------------------------
// fused prep (weight transpose+bf16) + per-dst edge count
// ---------------------------------------------------------------------------
__global__ void k_prep_count(const float* __restrict__ lin_W,
                             const float* __restrict__ linl_W,
                             const float* __restrict__ linr_W,
                             unsigned short* __restrict__ linWT,
                             unsigned short* __restrict__ WbT,
                             const int* __restrict__ eidx,
                             int* __restrict__ cnt) {
    const int b = blockIdx.x;
    const int t = threadIdx.x;
    if (b < CC) {
        linWT[b * CC + t]      = f2bf(lin_W[t * CC + b]);
        WbT[b * 512 + t]       = f2bf(linl_W[t * CC + b]);
        WbT[b * 512 + 256 + t] = f2bf(linr_W[t * CC + b]);
    } else {
        int e = (b - CC) * 256 + t;
        if (e < EE) atomicAdd(cnt + eidx[EE + e], 1);
    }
}

// ---------------------------------------------------------------------------
// m97-style MFMA GEMM: C[M x 256] = concat_k(A1, A2)[M x KTOT] @ B[KTOT x 256]
// 256 threads, 128x128 tile, BK=64, grid (M/128, 2).
// B (and A1 when A1BF16) staged via global_load_lds, linear LDS [128][64].
// A fp32 halves reg-staged with f2bf.
// ---------------------------------------------------------------------------
template <int KTOT, int OUTBF16, int A1BF16>
__global__ __launch_bounds__(256) void k_mmb(const float* __restrict__ A1f,
                                             const unsigned short* __restrict__ A1b,
                                             const float* __restrict__ A2f,
                                             const unsigned short* __restrict__ BT,
                                             const float* __restrict__ bias,
                                             float* __restrict__ Cf,
                                             unsigned short* __restrict__ Cb) {
    __shared__ unsigned short As[128 * 64];
    __shared__ unsigned short Bs[128 * 64];
    const int tid  = threadIdx.x;
    const int lane = tid & 63;
    const int wave = tid >> 6;      // 0..3
    const int wr   = wave >> 1;     // 0..1  (64-row half)
    const int wc   = wave & 1;      // 0..1  (64-col half)
    const int l15  = lane & 15;
    const int q4   = lane >> 4;
    const int lr8  = lane >> 3;     // row within an 8-row glds group
    const int lc8  = lane & 7;      // 16B slot within a 128B row
    const int i0   = blockIdx.x * 128;
    const int n0   = blockIdx.y * 128;

    floatx4 acc[4][4];
#pragma unroll
    for (int mt = 0; mt < 4; mt++)
#pragma unroll
        for (int nt = 0; nt < 4; nt++) acc[mt][nt] = (floatx4)0.0f;

    for (int kc = 0; kc < KTOT; kc += 64) {
        __syncthreads();
        const int first = (kc < 256);
        const int kco   = first ? kc : kc - 256;
        // ---- B tile: rows n0..n0+127, cols kc..kc+63 (bf16, row stride KTOT)
#pragma unroll
        for (int it = 0; it < 4; it++) {
            const int op = wave * 4 + it;    // 0..15, 8 rows each
            const unsigned short* g =
                BT + (size_t)(n0 + op * 8 + lr8) * KTOT + kc + lc8 * 8;
            GLDS16(g, Bs + op * 512);
        }
        // ---- A tile: rows i0..i0+127, cols kco..kco+63
        if (A1BF16 && first) {
#pragma unroll
            for (int it = 0; it < 4; it++) {
                const int op = wave * 4 + it;
                const unsigned short* g =
                    A1b + (size_t)(i0 + op * 8 + lr8) * CC + kc + lc8 * 8;
                GLDS16(g, As + op * 512);
            }
        } else {
            const float* af = first ? A1f : A2f;
#pragma unroll
            for (int w = 0; w < 4; w++) {
                const int q  = w * 256 + tid;   // 0..1023 16B-slots
                const int r  = q >> 3;          // row 0..127
                const int c8 = q & 7;           // 16B col
                const float* s = af + (size_t)(i0 + r) * CC + kco + c8 * 8;
                float4 v0 = *(const float4*)(s);
                float4 v1 = *(const float4*)(s + 4);
                uint4 p;
                p.x = (unsigned)f2bf(v0.x) | ((unsigned)f2bf(v0.y) << 16);
                p.y = (unsigned)f2bf(v0.z) | ((unsigned)f2bf(v0.w) << 16);
                p.z = (unsigned)f2bf(v1.x) | ((unsigned)f2bf(v1.y) << 16);
                p.w = (unsigned)f2bf(v1.z) | ((unsigned)f2bf(v1.w) << 16);
                *(uint4*)(As + r * 64 + c8 * 8) = p;
            }
        }
        __syncthreads();   // drains vmcnt(0): glds landed
#pragma unroll
        for (int kk = 0; kk < 64; kk += 32) {
            short8 a[4], b[4];
#pragma unroll
            for (int mt = 0; mt < 4; mt++)
                a[mt] = *(const short8*)(As + (wr * 64 + mt * 16 + l15) * 64 + kk + q4 * 8);
#pragma unroll
            for (int nt = 0; nt < 4; nt++)
                b[nt] = *(const short8*)(Bs + (wc * 64 + nt * 16 + l15) * 64 + kk + q4 * 8);
#pragma unroll
            for (int mt = 0; mt < 4; mt++)
#pragma unroll
                for (int nt = 0; nt < 4; nt++)
                    acc[mt][nt] = __builtin_amdgcn_mfma_f32_16x16x32_bf16(
                        a[mt], b[nt], acc[mt][nt], 0, 0, 0);
        }
    }
    // C/D layout: col=lane&15, row=(lane>>4)*4+reg  [verified m89/m91]
#pragma unroll
    for (int nt = 0; nt < 4; nt++) {
        const int col = n0 + wc * 64 + nt * 16 + l15;
        const float bz = bias[col];
#pragma unroll
        for (int mt = 0; mt < 4; mt++) {
#pragma unroll
            for (int r = 0; r < 4; r++) {
                const int row = i0 + wr * 64 + mt * 16 + q4 * 4 + r;
                const float v = acc[mt][nt][r] + bz;
                if (OUTBF16) Cb[(size_t)row * CC + col] = f2bf(v);
                else         Cf[(size_t)row * CC + col] = v;
            }
        }
    }
}

// ---------------------------------------------------------------------------
// CSR scan + scatter
// ---------------------------------------------------------------------------
#define SCAN_T 1024
#define SCHUNK 20
__global__ __launch_bounds__(1024) void k_scan(const int* __restrict__ cnt,
                                               int* __restrict__ offs,
                                               int* __restrict__ cursor) {
    __shared__ int ps[SCAN_T];
    const int t = threadIdx.x;
    const int base = t * SCHUNK;
    int s = 0;
#pragma unroll
    for (int i = 0; i < SCHUNK; i++) {
        int idx = base + i;
        if (idx < NN) s += cnt[idx];
    }
    ps[t] = s;
    __syncthreads();
    for (int off = 1; off < SCAN_T; off <<= 1) {
        int v = (t >= off) ? ps[t - off] : 0;
        __syncthreads();
        ps[t] += v;
        __syncthreads();
    }
    int excl = (t == 0) ? 0 : ps[t - 1];
#pragma unroll
    for (int i = 0; i < SCHUNK; i++) {
        int idx = base + i;
        if (idx < NN) {
            offs[idx]   = excl;
            cursor[idx] = excl;
            excl += cnt[idx];
        }
    }
    if (t == SCAN_T - 1) offs[NN] = ps[SCAN_T - 1];
}

__global__ void k_scatter(const int* __restrict__ eidx, int* __restrict__ cursor,
                          int* __restrict__ bucket) {
    int e = blockIdx.x * 256 + threadIdx.x;
    if (e < EE) {
        int d = eidx[EE + e];
        int p = atomicAdd(cursor + d, 1);
        bucket[p] = e;
    }
}

// ---------------------------------------------------------------------------
// gather-mean: block = node, thread = channel, 4 rc accumulators per lane.
// Round-0 vector-load body (scalarization reverted) + bond_W hoisted to regs
// + bf16 mean output (RNE-identical to k_mm staging's rounding).
// ---------------------------------------------------------------------------
__global__ __launch_bounds__(256) void k_agg(const unsigned short* __restrict__ xlb,
                                             const float* __restrict__ edge_attr,
                                             const float* __restrict__ ew,
                                             const float* __restrict__ bond_W,
                                             const float* __restrict__ bond_b,
                                             const int* __restrict__ eidx,
                                             const int* __restrict__ offs,
                                             const int* __restrict__ bucket,
                                             unsigned short* __restrict__ mean_b) {
    const int n = blockIdx.x;
    const int c = threadIdx.x;
    const int beg = offs[n], end = offs[n + 1];
    const float bb = bond_b[c];
    float bw[EDM];
#pragma unroll
    for (int k = 0; k < EDM; k++) bw[k] = bond_W[k * CC + c];   // loop-invariant

    float a0 = 0.f, a1 = 0.f, a2 = 0.f, a3 = 0.f;

#pragma unroll 2
    for (int j = beg; j < end; j++) {
        const int e   = bucket[j];
        const int src = eidx[e];
        const float w0 = ew[e];
        const float w1 = ew[EE + e];
        const float w2 = ew[2 * EE + e];
        const float w3 = ew[3 * EE + e];
        const float* ea = edge_attr + (size_t)e * EDM;
        float emb = bb;
#pragma unroll
        for (int k = 0; k < EDM; k++)
            emb = fmaf(ea[k], bw[k], emb);
        const size_t sb = (size_t)src * CC + c;
        float v0 = bf2f(xlb[sb])                       + emb;
        float v1 = bf2f(xlb[sb + (size_t)NN * CC])     + emb;
        float v2 = bf2f(xlb[sb + (size_t)2 * NN * CC]) + emb;
        float v3 = bf2f(xlb[sb + (size_t)3 * NN * CC]) + emb;
        a0 += gelu_fast(v0) * w0;
        a1 += gelu_fast(v1) * w1;
        a2 += gelu_fast(v2) * w2;
        a3 += gelu_fast(v3) * w3;
    }
    const float inv = 1.0f / fmaxf((float)(end - beg), 1.0f);
    const size_t ob = (size_t)n * CC + c;
    mean_b[ob]                       = f2bf(a0 * inv);
    mean_b[ob + (size_t)NN * CC]     = f2bf(a1 * inv);
    mean_b[ob + (size_t)2 * NN * CC] = f2bf(a2 * inv);
    mean_b[ob + (size_t)3 * NN * CC] = f2bf(a3 * inv);
}

extern "C" void kernel_launch(void* const* d_in, const int* in_sizes, int n_in,
                              void* d_out, int out_size, void* d_ws, size_t ws_size,
                              hipStream_t stream) {
    (void)in_sizes; (void)n_in; (void)out_size; (void)ws_size;
    const float* x           = (const float*)d_in[0];
    const float* edge_attr   = (const float*)d_in[1];
    const float* edge_weight = (const float*)d_in[2];
    const float* lin_W       = (const float*)d_in[3];
    const float* lin_b       = (const float*)d_in[4];
    const float* linl_W      = (const float*)d_in[5];
    const float* linl_b      = (const float*)d_in[6];
    const float* linr_W      = (const float*)d_in[7];
    const float* bond_W      = (const float*)d_in[8];
    const float* bond_b      = (const float*)d_in[9];
    const int*   edge_index  = (const int*)d_in[10];

    unsigned short* xlb   = (unsigned short*)d_ws;          // 80000*256 bf16
    unsigned short* linWT = xlb + (size_t)MTOT * CC;        // 256*256 bf16
    unsigned short* WbT   = linWT + CC * CC;                // 256*512 bf16
    int* cnt    = (int*)(WbT + CC * 512);                   // N
    int* offs   = cnt + NN;                                 // N+1
    int* cursor = offs + NN + 1;                            // N
    int* bucket = cursor + NN;                              // E
    // bf16 mean buffer, 256B-aligned (verified to fit in round 1: bf16 path ran)
    uintptr_t mb_addr = (((uintptr_t)(bucket + EE)) + 255) & ~(uintptr_t)255;
    unsigned short* mean_b = (unsigned short*)mb_addr;

    hipMemsetAsync(cnt, 0, NN * sizeof(int), stream);

    k_prep_count<<<CC + (EE + 255) / 256, 256, 0, stream>>>(
        lin_W, linl_W, linr_W, linWT, WbT, edge_index, cnt);
    // x_l(bf16) = x @ lin_W + lin_b   (A fp32 reg-staged, B via glds)
    k_mmb<256, 1, 0><<<dim3(MTOT / 128, 2), 256, 0, stream>>>(
        x, nullptr, nullptr, linWT, lin_b, nullptr, xlb);
    k_scan<<<1, SCAN_T, 0, stream>>>(cnt, offs, cursor);
    k_scatter<<<(EE + 255) / 256, 256, 0, stream>>>(edge_index, cursor, bucket);
    k_agg<<<NN, 256, 0, stream>>>(xlb, edge_attr, edge_weight, bond_W, bond_b,
                                  edge_index, offs, bucket, mean_b);
    // out = [mean | x] @ [linl; linr] + linl_b   (mean half via glds, x reg-staged)
    k_mmb<512, 0, 1><<<dim3(MTOT / 128, 2), 256, 0, stream>>>(
        nullptr, mean_b, x, WbT, linl_b, (float*)d_out, nullptr);
}